// Round 8
// baseline (134.985 us; speedup 1.0000x reference)
//
#include <hip/hip_runtime.h>

// HetConv via bf16 MFMA implicit GEMM, v8 = r2 geometry + counted-vmcnt pipeline (T4/T5).
// M=256 (perm p), N=128 px (2 rows x 64 cols), 256 thr = 4 waves (2 mrow x 2 ncol).
// Weights prepacked FRAGMENT-MAJOR (a-frag = base + lane*16B): DMA-legal linear copies,
// uniform 4 ops/thread/buffer, conflict-free ds_read_b128.
//
// Per-chunk schedule (3 raw s_barriers, derived vmcnt waits, never drain-0):
//   L0 : issue x-loads(k+1)                                   [+8 vm]
//   P1 : partA (32 MFMA, reads wh,xs) + taps0-3 (32 MFMA, reads wka,xs)
//   vmcnt(8); barrier         // guards wkb(k): newer = x8 only
//   issue DMA wh(k+1), wka(k+1)                               [+8 vm]
//   P2 : taps4-7 (32 MFMA, reads wkb,xs)
//   barrier
//   issue DMA wkb(k+1)                                        [+4 vm]
//   vmcnt(12)                 // x8(k+1) done (newer = wh4+wka4+wkb4)
//   XSW: ds_write xs(k+1)
//   vmcnt(4) lgkmcnt(0); barrier  // wh,wka(k+1) done (newer = wkb4); xs visible
// All 8 chunks run an IDENTICAL body (chunk 7 issues wraparound loads/DMAs into
// buffers nobody reads afterwards) -> per-wave vmcnt ledger uniform, tail-safe.

#define IN_C  256
#define OUT_C 256
#define HH    64
#define WW    64

typedef __attribute__((ext_vector_type(8))) short bf16x8;
typedef __attribute__((ext_vector_type(4))) short bf16x4;
typedef __attribute__((ext_vector_type(4))) float f32x4;

#define VM8()   asm volatile("s_waitcnt vmcnt(8)"  ::: "memory")
#define VM12()  asm volatile("s_waitcnt vmcnt(12)" ::: "memory")
#define VMLG4() asm volatile("s_waitcnt vmcnt(4) lgkmcnt(0)" ::: "memory")
#define VMLG0() asm volatile("s_waitcnt vmcnt(0) lgkmcnt(0)" ::: "memory")
#define SB()    __builtin_amdgcn_sched_barrier(0)
#define BAR()   __builtin_amdgcn_s_barrier()

__device__ __forceinline__ unsigned short f2bf(float f) {
    union { float f; unsigned int u; } v; v.f = f;
    unsigned int r = (v.u + 0x7FFFu + ((v.u >> 16) & 1u)) >> 16;
    return (unsigned short)r;
}

// ---------------- weight prepass (fragment-major) ----------------
// WH: [ck(8)][m(16)][lane(64)][e(8)]                      = 65536 el (16KB/chunk)
// WK: 65536 + [ck(8)][half(2)][tp(4)][bi(2)][mrow(2)][lane(64)][e(8)] = 131072 el
// decode: lrow=lane&15, kc=lane>>4; p=m*16+lrow; i=kc*8+e; g=ck&3, h2=ck>>2;
//         j=g+4*(32*h2+i); lo=bi*32+mrow*16+lrow; tf=half*4+tp; tfull=tf<4?tf:tf+1
__global__ __launch_bounds__(256)
void hetconv_prep(const float* __restrict__ Wk, const float* __restrict__ W1,
                  unsigned short* __restrict__ ws16) {
    const int TOTAL = 65536 + 131072;
    for (int idx = blockIdx.x * 256 + threadIdx.x; idx < TOTAL; idx += gridDim.x * 256) {
        float f;
        if (idx < 65536) {
            int e = idx & 7, lane = (idx >> 3) & 63, m = (idx >> 9) & 15, ck = idx >> 13;
            int g = ck & 3, h2 = ck >> 2;
            int p = m * 16 + (lane & 15);
            int i = (lane >> 4) * 8 + e;
            int j = g + 4 * (32 * h2 + i);
            int oc = 4 * (p & 63) + (p >> 6);
            f = ((p >> 6) == g) ? Wk[(oc * IN_C + j) * 9 + 4] : W1[oc * IN_C + j];
        } else {
            int k2 = idx - 65536;
            int e = k2 & 7, lane = (k2 >> 3) & 63;
            int mrow = (k2 >> 9) & 1, bi = (k2 >> 10) & 1, tp = (k2 >> 11) & 3;
            int hf = (k2 >> 13) & 1, ck = k2 >> 14;
            int g = ck & 3, h2 = ck >> 2;
            int tf = hf * 4 + tp, tfull = tf < 4 ? tf : tf + 1;
            int lo = bi * 32 + mrow * 16 + (lane & 15);
            int i = (lane >> 4) * 8 + e;
            int oc = 4 * lo + g;
            int j = g + 4 * (32 * h2 + i);
            f = Wk[(oc * IN_C + j) * 9 + tfull];
        }
        ws16[idx] = f2bf(f);
    }
}

// ---------------- main kernel helpers ----------------
#define XSPAD 36
#define XSSZ  (4 * 66 * XSPAD)   // 9504 el (19008 B)

__device__ __forceinline__ void stage_x_loads(const float* __restrict__ x, int n, int y0,
                                              int ck, int t, float4 v[4][2]) {
    const int g = ck & 3, h2 = ck >> 2;
    #pragma unroll
    for (int it = 0; it < 4; ++it) {
        int tau = t + it * 256;
        int icp = tau & 15, q = (tau >> 4) & 15, r = tau >> 8;
        int j0 = g + 4 * (32 * h2 + 2 * icp);
        int gy = y0 + r - 1;
        float4 z = {0.f, 0.f, 0.f, 0.f};
        v[it][0] = z; v[it][1] = z;
        if ((unsigned)gy < 64u) {
            const float* p0 = x + (((size_t)n * IN_C + j0) << 12) + (gy << 6) + (q << 2);
            v[it][0] = *(const float4*)p0;
            v[it][1] = *(const float4*)(p0 + 16384);   // plane j0+4
        }
    }
}

__device__ __forceinline__ void stage_x_writes(int t, float4 v[4][2], unsigned short* __restrict__ xb) {
    #pragma unroll
    for (int it = 0; it < 4; ++it) {
        int tau = t + it * 256;
        int icp = tau & 15, q = (tau >> 4) & 15, r = tau >> 8;
        unsigned d0 = (unsigned)f2bf(v[it][0].x) | ((unsigned)f2bf(v[it][1].x) << 16);
        unsigned d1 = (unsigned)f2bf(v[it][0].y) | ((unsigned)f2bf(v[it][1].y) << 16);
        unsigned d2 = (unsigned)f2bf(v[it][0].z) | ((unsigned)f2bf(v[it][1].z) << 16);
        unsigned d3 = (unsigned)f2bf(v[it][0].w) | ((unsigned)f2bf(v[it][1].w) << 16);
        int rb = (r * 66 + q * 4 + 1) * XSPAD + 2 * icp;
        *(unsigned*)&xb[rb]             = d0;
        *(unsigned*)&xb[rb + XSPAD]     = d1;
        *(unsigned*)&xb[rb + 2 * XSPAD] = d2;
        *(unsigned*)&xb[rb + 3 * XSPAD] = d3;
    }
}

// 16KB linear DMA: 1024 x 16B, 4 ops/thread (uniform across waves)
__device__ __forceinline__ void dma4(const unsigned short* __restrict__ src,
                                     unsigned short* __restrict__ dst, int t) {
    #pragma unroll
    for (int k = 0; k < 4; ++k) {
        int e = (t + k * 256) * 8;
        __builtin_amdgcn_global_load_lds(
            (const __attribute__((address_space(1))) unsigned int*)&src[e],
            (__attribute__((address_space(3))) unsigned int*)&dst[e], 16, 0, 0);
    }
}

__device__ __forceinline__ bf16x8 lds_bfrag(const unsigned short* __restrict__ xb, int off) {
    bf16x4 lo = *(const bf16x4*)&xb[off];
    bf16x4 hi = *(const bf16x4*)&xb[off + 4];
    return __builtin_shufflevector(lo, hi, 0, 1, 2, 3, 4, 5, 6, 7);
}

// Part A: dense pointwise. a-frag at wh[(mrow+2*mi)*512 + l*8] (lane-contiguous).
__device__ __forceinline__ void compute_A(const unsigned short* __restrict__ xb,
        const unsigned short* __restrict__ wh, f32x4 acc[8][4],
        int mrow, int ncol, int lrow, int kc, int l) {
    bf16x8 bfr[4];
    #pragma unroll
    for (int ni = 0; ni < 4; ++ni)
        bfr[ni] = lds_bfrag(xb, ((ncol + 1) * 66 + ni * 16 + lrow + 1) * XSPAD + kc * 8);
    #pragma unroll
    for (int mi = 0; mi < 8; ++mi) {
        bf16x8 a = *(const bf16x8*)&wh[(mrow + 2 * mi) * 512 + l * 8];
        #pragma unroll
        for (int ni = 0; ni < 4; ++ni)
            acc[mi][ni] = __builtin_amdgcn_mfma_f32_16x16x32_bf16(a, bfr[ni], acc[mi][ni], 0, 0, 0);
    }
}

// Part B tap-half: a-frags at wk[((tp*2+bi)*2+mrow)*512 + l*8] (lane-contiguous).
template <int G, int HALF>
__device__ __forceinline__ void compute_taps(const unsigned short* __restrict__ xb,
        const unsigned short* __restrict__ wk, f32x4 acc[8][4],
        int mrow, int ncol, int lrow, int kc, int l) {
    #pragma unroll
    for (int tp = 0; tp < 4; ++tp) {
        const int tf = HALF * 4 + tp;
        const int tfull = tf < 4 ? tf : tf + 1;
        const int dy = tfull / 3 - 1, dx = tfull % 3 - 1;
        bf16x8 a0 = *(const bf16x8*)&wk[((tp * 2 + 0) * 2 + mrow) * 512 + l * 8];
        bf16x8 a1 = *(const bf16x8*)&wk[((tp * 2 + 1) * 2 + mrow) * 512 + l * 8];
        #pragma unroll
        for (int ni = 0; ni < 4; ++ni) {
            bf16x8 bb = lds_bfrag(xb, ((ncol + 1 + dy) * 66 + ni * 16 + lrow + 1 + dx) * XSPAD + kc * 8);
            acc[2 * G + 0][ni] = __builtin_amdgcn_mfma_f32_16x16x32_bf16(a0, bb, acc[2 * G + 0][ni], 0, 0, 0);
            acc[2 * G + 1][ni] = __builtin_amdgcn_mfma_f32_16x16x32_bf16(a1, bb, acc[2 * G + 1][ni], 0, 0, 0);
        }
    }
}

// ---------------- main MFMA kernel ----------------
__global__ __launch_bounds__(256, 2)
void hetconv_mfma(const float* __restrict__ x,
                  const unsigned short* __restrict__ wgt,
                  float* __restrict__ out) {
    __shared__ __align__(16) unsigned short xs [XSSZ];   // 19008 B
    __shared__ __align__(16) unsigned short wh [8192];   // 16384 B
    __shared__ __align__(16) unsigned short wka[8192];   // 16384 B (taps 0-3)
    __shared__ __align__(16) unsigned short wkb[8192];   // 16384 B (taps 4-7)
                                                         // total 68160 B -> 2 blocks/CU
    const int t    = threadIdx.x;
    const int l    = t & 63;
    const int w    = t >> 6;
    const int mrow = w & 1;
    const int ncol = w >> 1;
    const int lrow = l & 15;
    const int kc   = l >> 4;

    const int bid = blockIdx.x;                 // 1024 blocks (r2-proven mapping)
    const int n   = (bid & 7) * 4 + (bid >> 8);
    const int y0  = ((bid >> 3) & 31) * 2;

    const unsigned short* WHg = wgt;
    const unsigned short* WKg = wgt + 65536;

    f32x4 acc[8][4];
    #pragma unroll
    for (int mi = 0; mi < 8; ++mi)
        #pragma unroll
        for (int ni = 0; ni < 4; ++ni) acc[mi][ni] = (f32x4){0.f, 0.f, 0.f, 0.f};

    // ---- prologue: issue everything for chunk 0, then one full drain ----
    {
        float4 xv[4][2];
        stage_x_loads(x, n, y0, 0, t, xv);      // +8
        dma4(WHg,            wh,  t);           // +4
        dma4(WKg,            wka, t);           // +4
        dma4(WKg + 8192,     wkb, t);           // +4
        if (t < 128) {   // zero halo cols (0,65): 4r x 2side x 16 dwords
            int r = t >> 5, side = (t >> 4) & 1, u = t & 15;
            *(unsigned*)&xs[(r * 66 + side * 65) * XSPAD + u * 2] = 0u;
        }
        VM12();                                  // x8(0) complete
        stage_x_writes(t, xv, xs);
        VMLG0(); SB(); BAR(); SB();              // all chunk-0 buffers ready
    }

    // ---- 8 identical chunk bodies (wraparound issues on the last) ----
#define CHUNK(CK)                                                               \
    {                                                                           \
        constexpr int nxt = ((CK) + 1) & 7;                                     \
        float4 xv[4][2];                                                        \
        stage_x_loads(x, n, y0, nxt, t, xv);            /* +8 */                \
        __builtin_amdgcn_s_setprio(1);                                          \
        compute_A(xs, wh, acc, mrow, ncol, lrow, kc, l);                        \
        compute_taps<(CK) & 3, 0>(xs, wka, acc, mrow, ncol, lrow, kc, l);       \
        __builtin_amdgcn_s_setprio(0);                                          \
        SB(); VM8(); BAR(); SB();               /* wkb(CK) ready (newer=x8) */  \
        dma4(WHg + nxt * 8192, wh, t);                  /* +4 */                \
        dma4(WKg + (nxt * 2 + 0) * 8192, wka, t);       /* +4 */                \
        SB();                                                                   \
        __builtin_amdgcn_s_setprio(1);                                          \
        compute_taps<(CK) & 3, 1>(xs, wkb, acc, mrow, ncol, lrow, kc, l);       \
        __builtin_amdgcn_s_setprio(0);                                          \
        SB(); BAR(); SB();                      /* xs/wkb reads done */         \
        dma4(WKg + (nxt * 2 + 1) * 8192, wkb, t);       /* +4 */                \
        SB(); VM12();                           /* x8(nxt) complete */          \
        stage_x_writes(t, xv, xs);                                              \
        VMLG4(); SB(); BAR(); SB();             /* wh,wka(nxt) done; xs vis */  \
    }

    CHUNK(0) CHUNK(1) CHUNK(2) CHUNK(3)
    CHUNK(4) CHUNK(5) CHUNK(6) CHUNK(7)
#undef CHUNK

    // ---- epilogue: C/D layout col=lane&15, row=(lane>>4)*4+reg ----
    #pragma unroll
    for (int mi = 0; mi < 8; ++mi) {
        int m = mrow + 2 * mi;
        #pragma unroll
        for (int ni = 0; ni < 4; ++ni) {
            #pragma unroll
            for (int reg = 0; reg < 4; ++reg) {
                int p  = m * 16 + kc * 4 + reg;
                int oc = 4 * (p & 63) + (p >> 6);
                out[(((size_t)n * OUT_C + oc) * HH + (y0 + ncol)) * WW + ni * 16 + lrow] = acc[mi][ni][reg];
            }
        }
    }
}

// ---------------- fp32 fallback (only if ws too small) ----------------
#define TH 16
#define TW 16
#define ICC 16
__global__ __launch_bounds__(256)
void hetconv_fp32(const float* __restrict__ x,
                  const float* __restrict__ Wk,
                  const float* __restrict__ W1,
                  float* __restrict__ out) {
    const int t    = threadIdx.x;
    const int g    = blockIdx.y;
    const int n    = blockIdx.z;
    const int tile = blockIdx.x;
    const int ty0  = (tile >> 2) * TH;
    const int tx0  = (tile & 3) * TW;
    const int ol = t & 7;
    const int pl = t >> 3;
    const int r  = pl >> 1;
    const int ch = (pl & 1) * 8;
    __shared__ __align__(16) float xsf[ICC * 18 * 20];
    __shared__ __align__(16) float w1s[ICC * 64];
    __shared__ __align__(16) float wksf[4 * 9 * 64];
    float acc[8][8];
    #pragma unroll
    for (int k = 0; k < 8; ++k)
        #pragma unroll
        for (int p = 0; p < 8; ++p) acc[k][p] = 0.f;
    for (int ic0 = 0; ic0 < IN_C; ic0 += ICC) {
        for (int idx = t; idx < ICC * 18 * 18; idx += 256) {
            int ic = idx / 324, rem = idx - ic * 324, rr = rem / 18, cc = rem - rr * 18;
            int gy = ty0 + rr - 1, gx = tx0 + cc - 1;
            float v = 0.f;
            if (gy >= 0 && gy < HH && gx >= 0 && gx < WW)
                v = x[(((size_t)n * IN_C + ic0 + ic) * HH + gy) * WW + gx];
            xsf[ic * 360 + rr * 20 + cc] = v;
        }
        for (int idx = t; idx < ICC * 64; idx += 256) {
            int ic = idx >> 6, o = idx & 63;
            w1s[idx] = W1[(g + 4 * o) * IN_C + ic0 + ic];
        }
        for (int idx = t; idx < 4 * 9 * 64; idx += 256) {
            int a = idx / 576, rem = idx - a * 576, tap = rem >> 6, o = rem & 63;
            wksf[idx] = Wk[((g + 4 * o) * IN_C + ic0 + g + 4 * a) * 9 + tap];
        }
        __syncthreads();
        for (int ic = 0; ic < ICC; ++ic) {
            if ((ic & 3) != g) {
                const float* rowp = &xsf[ic * 360 + (r + 1) * 20 + ch];
                float4 A = *(const float4*)rowp;
                float4 B = *(const float4*)(rowp + 4);
                float  c8 = rowp[8];
                float xv[8] = {A.y, A.z, A.w, B.x, B.y, B.z, B.w, c8};
                const float* wp = &w1s[ic * 64 + ol * 8];
                float4 wA = *(const float4*)wp;
                float4 wB = *(const float4*)(wp + 4);
                float wv[8] = {wA.x, wA.y, wA.z, wA.w, wB.x, wB.y, wB.z, wB.w};
                #pragma unroll
                for (int k = 0; k < 8; ++k)
                    #pragma unroll
                    for (int p = 0; p < 8; ++p) acc[k][p] += wv[k] * xv[p];
            } else {
                const int a = ic >> 2;
                #pragma unroll
                for (int dy = -1; dy <= 1; ++dy) {
                    const float* rowp = &xsf[ic * 360 + (r + 1 + dy) * 20 + ch];
                    float4 A = *(const float4*)rowp;
                    float4 B = *(const float4*)(rowp + 4);
                    float2 C = *(const float2*)(rowp + 8);
                    float seg[10] = {A.x, A.y, A.z, A.w, B.x, B.y, B.z, B.w, C.x, C.y};
                    #pragma unroll
                    for (int dxi = 0; dxi < 3; ++dxi) {
                        const float* wp = &wksf[(a * 9 + (dy + 1) * 3 + dxi) * 64 + ol * 8];
                        float4 wA = *(const float4*)wp;
                        float4 wB = *(const float4*)(wp + 4);
                        float wv[8] = {wA.x, wA.y, wA.z, wA.w, wB.x, wB.y, wB.z, wB.w};
                        #pragma unroll
                        for (int k = 0; k < 8; ++k)
                            #pragma unroll
                            for (int p = 0; p < 8; ++p) acc[k][p] += wv[k] * seg[p + dxi];
                    }
                }
            }
        }
        __syncthreads();
    }
    #pragma unroll
    for (int k = 0; k < 8; ++k) {
        int oc = g + 4 * (ol * 8 + k);
        size_t base = (((size_t)n * OUT_C + oc) * HH + (ty0 + r)) * WW + tx0 + ch;
        float4 v0 = {acc[k][0], acc[k][1], acc[k][2], acc[k][3]};
        float4 v1 = {acc[k][4], acc[k][5], acc[k][6], acc[k][7]};
        *(float4*)(&out[base])     = v0;
        *(float4*)(&out[base + 4]) = v1;
    }
}

extern "C" void kernel_launch(void* const* d_in, const int* in_sizes, int n_in,
                              void* d_out, int out_size, void* d_ws, size_t ws_size,
                              hipStream_t stream) {
    const float* x  = (const float*)d_in[0];
    const float* Wk = (const float*)d_in[1];
    const float* W1 = (const float*)d_in[2];
    float* outp = (float*)d_out;

    if (ws_size >= (size_t)(65536 + 131072) * sizeof(unsigned short)) {
        hetconv_prep<<<240, 256, 0, stream>>>(Wk, W1, (unsigned short*)d_ws);
        hetconv_mfma<<<1024, 256, 0, stream>>>(x, (const unsigned short*)d_ws, outp);
    } else {
        hetconv_fp32<<<dim3(16, 4, 32), 256, 0, stream>>>(x, Wk, W1, outp);
    }
}

// Round 9
// 100.650 us; speedup vs baseline: 1.3411x; 1.3411x over previous
//
#include <hip/hip_runtime.h>
#include <hip/hip_bf16.h>

// HetConv via bf16 MFMA implicit GEMM, v9 = r2 (best: 105us) + two surgical fixes:
//   1) packed f32x2->bf16x2 convert (__float22bfloat162_rn) -- cuts staging VALU ~4x
//   2) T14-lite: global loads hoisted one phase earlier (x loads for k+1 overlap
//      tapsB(k); wh/wka loads overlap x cvt+writes; wkb loads overlap partA+tapsA)
// NO structural change: same 4 barriers/chunk, same buffers, same 1024-block mapping,
// same pad-40 LDS layouts (b128 frag reads, stride-5 16B slots = conflict-free).

#define IN_C  256
#define OUT_C 256
#define HH    64
#define WW    64

typedef __attribute__((ext_vector_type(8))) short bf16x8;
typedef __attribute__((ext_vector_type(4))) float f32x4;

__device__ __forceinline__ unsigned short f2bf(float f) {
    union { float f; unsigned int u; } v; v.f = f;
    unsigned int r = (v.u + 0x7FFFu + ((v.u >> 16) & 1u)) >> 16;
    return (unsigned short)r;
}

__device__ __forceinline__ unsigned pkbf(float lo, float hi) {
    union { __hip_bfloat162 b; unsigned u; } c;
    c.b = __float22bfloat162_rn(make_float2(lo, hi));
    return c.u;
}

// ---------------- weight prepass (identical to r2) ----------------
// What: [h=0..7][p=0..255][40]                      (h = h2*4+g ; j = g+4*(32*h2+i))
// Wkt : offset 81920: [h][tap=0..7][lo=0..63][40]   (tap_full = tap<4 ? tap : tap+1)
__global__ __launch_bounds__(256)
void hetconv_prep(const float* __restrict__ Wk, const float* __restrict__ W1,
                  unsigned short* __restrict__ ws16) {
    const int total = 81920 + 163840;
    for (int idx = blockIdx.x * 256 + threadIdx.x; idx < total; idx += gridDim.x * 256) {
        float f = 0.f;
        if (idx < 81920) {
            int i = idx % 40;
            int p = (idx / 40) & 255;
            int h = idx / 10240;
            int g = h & 3, h2 = h >> 2;
            if (i < 32) {
                int j  = g + 4 * (32 * h2 + i);
                int oc = 4 * (p & 63) + (p >> 6);
                f = ((p >> 6) == g) ? Wk[(oc * IN_C + j) * 9 + 4] : W1[oc * IN_C + j];
            }
        } else {
            int widx = idx - 81920;
            int i   = widx % 40;
            int lo  = (widx / 40) & 63;
            int tap = (widx / 2560) & 7;
            int h   = widx / 20480;
            int g = h & 3, h2 = h >> 2;
            if (i < 32) {
                int j  = g + 4 * (32 * h2 + i);
                int oc = 4 * lo + g;
                int tf = tap < 4 ? tap : tap + 1;
                f = Wk[(oc * IN_C + j) * 9 + tf];
            }
        }
        ws16[idx] = f2bf(f);
    }
}

// ---------------- main kernel helpers ----------------
// x chunk: 32 ic x 4 rows x 64 cols. tasks [r(4)][q(16)][icp(16)] = 1024 = 256*4
__device__ __forceinline__ void stage_x_loads(const float* __restrict__ x, int n, int y0,
                                              int ck, int t, float4 v[4][2]) {
    const int g = ck & 3, h2 = ck >> 2;
    #pragma unroll
    for (int it = 0; it < 4; ++it) {
        int tau = t + it * 256;
        int icp = tau & 15, q = (tau >> 4) & 15, r = tau >> 8;
        int i0 = icp * 2;
        int j0 = g + 4 * (32 * h2 + i0);
        int gy = y0 + r - 1;
        float4 z = {0.f, 0.f, 0.f, 0.f};
        v[it][0] = z; v[it][1] = z;
        if ((unsigned)gy < 64u) {
            const float* p0 = x + (((size_t)n * IN_C + j0) << 12) + (gy << 6) + (q << 2);
            v[it][0] = *(const float4*)p0;
            v[it][1] = *(const float4*)(p0 + 16384);   // plane j0+4 (K elem i0+1)
        }
    }
}

__device__ __forceinline__ void stage_x_writes(int t, float4 v[4][2], unsigned short* __restrict__ xb) {
    #pragma unroll
    for (int it = 0; it < 4; ++it) {
        int tau = t + it * 256;
        int icp = tau & 15, q = (tau >> 4) & 15, r = tau >> 8;
        int i0 = icp * 2;
        unsigned d0 = pkbf(v[it][0].x, v[it][1].x);
        unsigned d1 = pkbf(v[it][0].y, v[it][1].y);
        unsigned d2 = pkbf(v[it][0].z, v[it][1].z);
        unsigned d3 = pkbf(v[it][0].w, v[it][1].w);
        int rb = (r * 66 + q * 4 + 1) * 40 + i0;
        *(unsigned*)&xb[rb]        = d0;
        *(unsigned*)&xb[rb + 40]   = d1;
        *(unsigned*)&xb[rb + 80]   = d2;
        *(unsigned*)&xb[rb + 120]  = d3;
    }
}

// ---------------- main MFMA kernel ----------------
// Block: 256 thr (4 waves, 2 mrow x 2 ncol). Computes all 256 oc x 128 px
// (2 output rows x 64 cols) for one (n, ytile). K-loop: 8 chunks of 32 ic.
__global__ __launch_bounds__(256, 2)
void hetconv_mfma(const float* __restrict__ x,
                  const unsigned short* __restrict__ wsw,
                  float* __restrict__ out) {
    __shared__ unsigned short xs[4 * 66 * 40];   // 21120 B  [r][c 0..65][ic pad40]
    __shared__ unsigned short wh[256 * 40];      // 20480 B  W_hat chunk [p][i pad40]
    __shared__ unsigned short wk[4 * 64 * 40];   // 20480 B  4 taps [tap][lo][i pad40]

    const int t    = threadIdx.x;
    const int l    = t & 63;
    const int w    = t >> 6;
    const int mrow = w & 1;
    const int ncol = w >> 1;
    const int lrow = l & 15;
    const int kc   = l >> 4;

    const int bid = blockIdx.x;                 // 1024 blocks (r2-proven mapping)
    const int n   = (bid & 7) * 4 + (bid >> 8);
    const int y0  = ((bid >> 3) & 31) * 2;

    f32x4 acc[8][4];
    #pragma unroll
    for (int mi = 0; mi < 8; ++mi)
        #pragma unroll
        for (int ni = 0; ni < 4; ++ni) acc[mi][ni] = (f32x4){0.f, 0.f, 0.f, 0.f};

    // ---- prologue: zero halo cols (never re-written) + hoist chunk-0 x loads ----
    if (t < 128) {
        int r = t >> 5, side = (t >> 4) & 1, u = t & 15;
        *(unsigned*)&xs[(r * 66 + side * 65) * 40 + u * 2] = 0u;
    }
    float4 xv[4][2];
    stage_x_loads(x, n, y0, 0, t, xv);

    // ---- 8 chunks, 4 barriers each (r2 structure), loads hoisted one phase ----
#define CHUNK(CK, LAST)                                                             \
    {                                                                               \
        const unsigned short* hs = wsw + (CK) * 10240;                              \
        const unsigned short* ks = wsw + 81920 + (CK) * 20480;                      \
        __syncthreads();                       /* (1) tapsB(prev) done with xs */   \
        bf16x8 wv[10];                                                              \
        _Pragma("unroll")                                                           \
        for (int it = 0; it < 5; ++it) {       /* wh+wka loads first (overlap) */   \
            int e = (t + it * 256) * 8;                                             \
            wv[it]     = *(const bf16x8*)&hs[e];                                    \
            wv[5 + it] = *(const bf16x8*)&ks[e];                                    \
        }                                                                           \
        stage_x_writes(t, xv, xs);             /* cvt_pk + ds_write (covers wv) */  \
        _Pragma("unroll")                                                           \
        for (int it = 0; it < 5; ++it) {                                            \
            int e = (t + it * 256) * 8;                                             \
            *(bf16x8*)&wh[e] = wv[it];                                              \
            *(bf16x8*)&wk[e] = wv[5 + it];                                          \
        }                                                                           \
        __syncthreads();                       /* (2) xs, wh, wka ready */          \
        bf16x8 wvb[5];                                                              \
        _Pragma("unroll")                                                           \
        for (int it = 0; it < 5; ++it)         /* wkb loads (overlap compute) */    \
            wvb[it] = *(const bf16x8*)&ks[10240 + (t + it * 256) * 8];              \
        {   /* part A: dense pointwise, K=32 */                                     \
            bf16x8 a[8], b[4];                                                      \
            _Pragma("unroll")                                                       \
            for (int mi = 0; mi < 8; ++mi) {                                        \
                int m = mrow + 2 * mi;                                              \
                a[mi] = *(const bf16x8*)&wh[(m * 16 + lrow) * 40 + kc * 8];         \
            }                                                                       \
            _Pragma("unroll")                                                       \
            for (int ni = 0; ni < 4; ++ni)                                          \
                b[ni] = *(const bf16x8*)&xs[((ncol + 1) * 66 + ni * 16 + lrow + 1) * 40 + kc * 8]; \
            _Pragma("unroll")                                                       \
            for (int mi = 0; mi < 8; ++mi)                                          \
                _Pragma("unroll")                                                   \
                for (int ni = 0; ni < 4; ++ni)                                      \
                    acc[mi][ni] = __builtin_amdgcn_mfma_f32_16x16x32_bf16(a[mi], b[ni], acc[mi][ni], 0, 0, 0); \
        }                                                                           \
        {   /* part B taps 0-3 (tap_full 0..3) */                                   \
            constexpr int G = (CK) & 3;                                             \
            _Pragma("unroll")                                                       \
            for (int tp = 0; tp < 4; ++tp) {                                        \
                const int dy = tp / 3 - 1, dx = tp % 3 - 1;                         \
                bf16x8 a0 = *(const bf16x8*)&wk[(tp * 64 + mrow * 16 + lrow) * 40 + kc * 8]; \
                bf16x8 a1 = *(const bf16x8*)&wk[(tp * 64 + (mrow + 2) * 16 + lrow) * 40 + kc * 8]; \
                _Pragma("unroll")                                                   \
                for (int ni = 0; ni < 4; ++ni) {                                    \
                    bf16x8 bb = *(const bf16x8*)&xs[((ncol + 1 + dy) * 66 + ni * 16 + lrow + 1 + dx) * 40 + kc * 8]; \
                    acc[2 * G + 0][ni] = __builtin_amdgcn_mfma_f32_16x16x32_bf16(a0, bb, acc[2 * G + 0][ni], 0, 0, 0); \
                    acc[2 * G + 1][ni] = __builtin_amdgcn_mfma_f32_16x16x32_bf16(a1, bb, acc[2 * G + 1][ni], 0, 0, 0); \
                }                                                                   \
            }                                                                       \
        }                                                                           \
        __syncthreads();                       /* (3) wka reads done */             \
        _Pragma("unroll")                                                           \
        for (int it = 0; it < 5; ++it)                                              \
            *(bf16x8*)&wk[(t + it * 256) * 8] = wvb[it];                            \
        if (!(LAST)) stage_x_loads(x, n, y0, (CK) + 1, t, xv);  /* overlap tapsB */ \
        __syncthreads();                       /* (4) wkb ready */                  \
        {   /* part B taps 4-7 (tap_full 5..8) */                                   \
            constexpr int G = (CK) & 3;                                             \
            _Pragma("unroll")                                                       \
            for (int tp = 0; tp < 4; ++tp) {                                        \
                const int tf = tp + 5;                                              \
                const int dy = tf / 3 - 1, dx = tf % 3 - 1;                         \
                bf16x8 a0 = *(const bf16x8*)&wk[(tp * 64 + mrow * 16 + lrow) * 40 + kc * 8]; \
                bf16x8 a1 = *(const bf16x8*)&wk[(tp * 64 + (mrow + 2) * 16 + lrow) * 40 + kc * 8]; \
                _Pragma("unroll")                                                   \
                for (int ni = 0; ni < 4; ++ni) {                                    \
                    bf16x8 bb = *(const bf16x8*)&xs[((ncol + 1 + dy) * 66 + ni * 16 + lrow + 1 + dx) * 40 + kc * 8]; \
                    acc[2 * G + 0][ni] = __builtin_amdgcn_mfma_f32_16x16x32_bf16(a0, bb, acc[2 * G + 0][ni], 0, 0, 0); \
                    acc[2 * G + 1][ni] = __builtin_amdgcn_mfma_f32_16x16x32_bf16(a1, bb, acc[2 * G + 1][ni], 0, 0, 0); \
                }                                                                   \
            }                                                                       \
        }                                                                           \
    }

    CHUNK(0, 0) CHUNK(1, 0) CHUNK(2, 0) CHUNK(3, 0)
    CHUNK(4, 0) CHUNK(5, 0) CHUNK(6, 0) CHUNK(7, 1)
#undef CHUNK

    // ---- epilogue: C/D layout col=lane&15, row=(lane>>4)*4+reg ----
    #pragma unroll
    for (int mi = 0; mi < 8; ++mi) {
        int m = mrow + 2 * mi;
        #pragma unroll
        for (int ni = 0; ni < 4; ++ni) {
            #pragma unroll
            for (int reg = 0; reg < 4; ++reg) {
                int p  = m * 16 + kc * 4 + reg;
                int oc = 4 * (p & 63) + (p >> 6);
                out[(((size_t)n * OUT_C + oc) * HH + (y0 + ncol)) * WW + ni * 16 + lrow] = acc[mi][ni][reg];
            }
        }
    }
}

// ---------------- fp32 fallback (only if ws too small) ----------------
#define TH 16
#define TW 16
#define ICC 16
__global__ __launch_bounds__(256)
void hetconv_fp32(const float* __restrict__ x,
                  const float* __restrict__ Wk,
                  const float* __restrict__ W1,
                  float* __restrict__ out) {
    const int t    = threadIdx.x;
    const int g    = blockIdx.y;
    const int n    = blockIdx.z;
    const int tile = blockIdx.x;
    const int ty0  = (tile >> 2) * TH;
    const int tx0  = (tile & 3) * TW;
    const int ol = t & 7;
    const int pl = t >> 3;
    const int r  = pl >> 1;
    const int ch = (pl & 1) * 8;
    __shared__ __align__(16) float xsf[ICC * 18 * 20];
    __shared__ __align__(16) float w1s[ICC * 64];
    __shared__ __align__(16) float wksf[4 * 9 * 64];
    float acc[8][8];
    #pragma unroll
    for (int k = 0; k < 8; ++k)
        #pragma unroll
        for (int p = 0; p < 8; ++p) acc[k][p] = 0.f;
    for (int ic0 = 0; ic0 < IN_C; ic0 += ICC) {
        for (int idx = t; idx < ICC * 18 * 18; idx += 256) {
            int ic = idx / 324, rem = idx - ic * 324, rr = rem / 18, cc = rem - rr * 18;
            int gy = ty0 + rr - 1, gx = tx0 + cc - 1;
            float v = 0.f;
            if (gy >= 0 && gy < HH && gx >= 0 && gx < WW)
                v = x[(((size_t)n * IN_C + ic0 + ic) * HH + gy) * WW + gx];
            xsf[ic * 360 + rr * 20 + cc] = v;
        }
        for (int idx = t; idx < ICC * 64; idx += 256) {
            int ic = idx >> 6, o = idx & 63;
            w1s[idx] = W1[(g + 4 * o) * IN_C + ic0 + ic];
        }
        for (int idx = t; idx < 4 * 9 * 64; idx += 256) {
            int a = idx / 576, rem = idx - a * 576, tap = rem >> 6, o = rem & 63;
            wksf[idx] = Wk[((g + 4 * o) * IN_C + ic0 + g + 4 * a) * 9 + tap];
        }
        __syncthreads();
        for (int ic = 0; ic < ICC; ++ic) {
            if ((ic & 3) != g) {
                const float* rowp = &xsf[ic * 360 + (r + 1) * 20 + ch];
                float4 A = *(const float4*)rowp;
                float4 B = *(const float4*)(rowp + 4);
                float  c8 = rowp[8];
                float xv2[8] = {A.y, A.z, A.w, B.x, B.y, B.z, B.w, c8};
                const float* wp = &w1s[ic * 64 + ol * 8];
                float4 wA = *(const float4*)wp;
                float4 wB = *(const float4*)(wp + 4);
                float wv2[8] = {wA.x, wA.y, wA.z, wA.w, wB.x, wB.y, wB.z, wB.w};
                #pragma unroll
                for (int k = 0; k < 8; ++k)
                    #pragma unroll
                    for (int p = 0; p < 8; ++p) acc[k][p] += wv2[k] * xv2[p];
            } else {
                const int a = ic >> 2;
                #pragma unroll
                for (int dy = -1; dy <= 1; ++dy) {
                    const float* rowp = &xsf[ic * 360 + (r + 1 + dy) * 20 + ch];
                    float4 A = *(const float4*)rowp;
                    float4 B = *(const float4*)(rowp + 4);
                    float2 C = *(const float2*)(rowp + 8);
                    float seg[10] = {A.x, A.y, A.z, A.w, B.x, B.y, B.z, B.w, C.x, C.y};
                    #pragma unroll
                    for (int dxi = 0; dxi < 3; ++dxi) {
                        const float* wp = &wksf[(a * 9 + (dy + 1) * 3 + dxi) * 64 + ol * 8];
                        float4 wA = *(const float4*)wp;
                        float4 wB = *(const float4*)(wp + 4);
                        float wv2[8] = {wA.x, wA.y, wA.z, wA.w, wB.x, wB.y, wB.z, wB.w};
                        #pragma unroll
                        for (int k = 0; k < 8; ++k)
                            #pragma unroll
                            for (int p = 0; p < 8; ++p) acc[k][p] += wv2[k] * seg[p + dxi];
                    }
                }
            }
        }
        __syncthreads();
    }
    #pragma unroll
    for (int k = 0; k < 8; ++k) {
        int oc = g + 4 * (ol * 8 + k);
        size_t base = (((size_t)n * OUT_C + oc) * HH + (ty0 + r)) * WW + tx0 + ch;
        float4 v0 = {acc[k][0], acc[k][1], acc[k][2], acc[k][3]};
        float4 v1 = {acc[k][4], acc[k][5], acc[k][6], acc[k][7]};
        *(float4*)(&out[base])     = v0;
        *(float4*)(&out[base + 4]) = v1;
    }
}

extern "C" void kernel_launch(void* const* d_in, const int* in_sizes, int n_in,
                              void* d_out, int out_size, void* d_ws, size_t ws_size,
                              hipStream_t stream) {
    const float* x  = (const float*)d_in[0];
    const float* Wk = (const float*)d_in[1];
    const float* W1 = (const float*)d_in[2];
    float* outp = (float*)d_out;

    if (ws_size >= (size_t)(81920 + 163840) * sizeof(unsigned short)) {
        hetconv_prep<<<240, 256, 0, stream>>>(Wk, W1, (unsigned short*)d_ws);
        hetconv_mfma<<<1024, 256, 0, stream>>>(x, (const unsigned short*)d_ws, outp);
    } else {
        hetconv_fp32<<<dim3(16, 4, 32), 256, 0, stream>>>(x, Wk, W1, outp);
    }
}